// Round 5
// baseline (135.691 us; speedup 1.0000x reference)
//
#include <hip/hip_runtime.h>
#include <math.h>

// Problem constants (match reference)
constexpr int BN = 128;
constexpr int FH = 26, FW = 26;
constexpr int T  = 50;
constexpr int A  = 5;
constexpr int NC = 20;
constexpr int K  = FH * FW;      // 676
constexpr int KA = K * A;        // 3380
constexpr int CH = A * (5 + NC); // 125

constexpr float IGNORE_THRESH = 0.75f;
constexpr float OBJ_SCALE = 5.0f;
// NOOBJ_SCALE = 1.0 (folded into the math)

constexpr int GCH  = (KA + 255) / 256;  // 14 chunks of 256 slots per batch
constexpr int NBLK = BN * GCH;          // 1792 main blocks

__constant__ float ANCW[A] = {1.3221f, 3.19275f, 5.05587f, 9.47112f, 11.2364f};
__constant__ float ANCH[A] = {1.73145f, 4.00944f, 8.09892f, 4.84053f, 10.0071f};

__device__ __forceinline__ float fast_sigmoid(float x) {
    return __builtin_amdgcn_rcpf(1.0f + __expf(-x));
}

// ---------------------------------------------------------------------------
// K0: per-GT decode, one thread per (b,t). Writes two 8-float records per GT:
//   giou[b][t] = {x1,y1,x2,y2, area, slot_as_float, 0,0}  (degenerate if invalid)
//   gtb [b][t] = {tb0,tb1,tb2,tb3, cls, 0,0,0}
// 8-float stride => 32B-aligned, s_load_dwordx8-friendly uniform reads in K1.
// Also zero-inits the completion counter used by K1's last-block reduce.
// ---------------------------------------------------------------------------
__global__ __launch_bounds__(256) void yolo_prep(
        const float* __restrict__ targets,
        float* __restrict__ giou, float* __restrict__ gtb,
        unsigned* __restrict__ cnt) {
    int i = blockIdx.x * 256 + threadIdx.x;
    if (i == 0) *cnt = 0u;
    if (i >= BN * T) return;

    const float* g = targets + (size_t)i * 5;
    float rx1 = g[0], ry1 = g[1], rx2 = g[2], ry2 = g[3];
    bool valid = (rx1 + ry1 + rx2 + ry2) > 0.0f;
    float x1 = rx1 * FW, y1 = ry1 * FH, x2 = rx2 * FW, y2 = ry2 * FH;
    float w = x2 - x1, h = y2 - y1;

    float cxf = 0.5f * (x1 + x2), cyf = 0.5f * (y1 + y2);
    int cx = (int)floorf(cxf); cx = min(max(cx, 0), FW - 1);
    int cy = (int)floorf(cyf); cy = min(max(cy, 0), FH - 1);
    int cell = cy * FW + cx;

    // argmax over anchors (strict > => first max wins) of IoU(anchor@center, gt)
    float acx = (float)cx + 0.5f, acy = (float)cy + 0.5f;
    float best = -1.0f; int ai = 0;
    for (int a = 0; a < A; ++a) {
        float aw = ANCW[a], ah = ANCH[a];
        float xi1 = fmaxf(acx - 0.5f * aw, x1), yi1 = fmaxf(acy - 0.5f * ah, y1);
        float xi2 = fminf(acx + 0.5f * aw, x2), yi2 = fminf(acy + 0.5f * ah, y2);
        float inter = fmaxf(xi2 - xi1, 0.0f) * fmaxf(yi2 - yi1, 0.0f);
        float iou = inter / (aw * ah + w * h - inter);
        if (iou > best) { best = iou; ai = a; }
    }

    float4 p0, p1;
    if (valid) {
        p0 = make_float4(x1, y1, x2, y2);
        p1 = make_float4(w * h, __int_as_float(ai * K + cell), 0.0f, 0.0f);
    } else {
        p0 = make_float4(1e18f, 1e18f, -1e18f, -1e18f);  // inter -> 0
        p1 = make_float4(1.0f, __int_as_float(-1), 0.0f, 0.0f);
    }
    *(float4*)(giou + (size_t)i * 8)     = p0;
    *(float4*)(giou + (size_t)i * 8 + 4) = p1;
    *(float4*)(gtb  + (size_t)i * 8)     = make_float4(cxf - (float)cx, cyf - (float)cy,
                                                       w / ANCW[ai], h / ANCH[ai]);
    *(float4*)(gtb  + (size_t)i * 8 + 4) = make_float4(g[4], 0.0f, 0.0f, 0.0f);
}

// ---------------------------------------------------------------------------
// K1: main pass. grid (GCH, BN) = 1792 blocks, one thread per slot.
// GT records are read with wave-uniform global addresses -> scalar (s_load)
// path, no LDS staging, no decode phase, no barrier before the loop.
// Winner = last t whose assigned slot matches (== lax.scan overwrite).
// pos_any deferred: noobj term added unconditionally; subset with m>=thresh
// also summed into Mp. The LAST block to finish (device atomic counter)
// reduces all partials and stores:  out = [ sum_b (L_b - any_b * M_b) ] / BN
// ---------------------------------------------------------------------------
__global__ __launch_bounds__(256) void yolo_main(
        const float* __restrict__ outputs,   // (B, 125, 26, 26)
        const float* __restrict__ giou, const float* __restrict__ gtb,
        float* __restrict__ Lp, float* __restrict__ Mp, int* __restrict__ Anyp,
        unsigned* __restrict__ cnt, float* __restrict__ out) {
    __shared__ float redl[4], redm[4];
    __shared__ int   reda[4];
    __shared__ int   lastFlag;

    const int b   = blockIdx.y;
    const int tid = threadIdx.x;
    const int s   = blockIdx.x * 256 + tid;
    const bool live = s < KA;

    float loss = 0.0f, masked = 0.0f;
    int anyf = 0;

    if (live) {
        const int a = s / K, k = s - a * K;
        const int y = k / FW, x = k - y * FW;
        const float* ob = outputs + (size_t)b * CH * K + (size_t)(a * 25) * K;

        float o0 = ob[0 * K + k];
        float o1 = ob[1 * K + k];
        float o2 = ob[2 * K + k];
        float o3 = ob[3 * K + k];
        float o4 = ob[4 * K + k];

        float s0 = fast_sigmoid(o0), s1 = fast_sigmoid(o1);
        float e2 = __expf(o2),       e3 = __expf(o3);
        float px = (float)x + s0, py = (float)y + s1;
        float pw = ANCW[a] * e2,  ph = ANCH[a] * e3;
        float px1 = px - 0.5f * pw, px2 = px + 0.5f * pw;
        float py1 = py - 0.5f * ph, py2 = py + 0.5f * ph;
        float parea = pw * ph;

        // wave-uniform base: compiler emits scalar loads for gb[uniform idx]
        const float* gb = giou + (size_t)b * T * 8;

        float m = -1.0f;
        int w = -1;
        #pragma unroll 10
        for (int t = 0; t < T; ++t) {
            float bx1 = gb[t * 8 + 0], by1 = gb[t * 8 + 1];
            float bx2 = gb[t * 8 + 2], by2 = gb[t * 8 + 3];
            float area = gb[t * 8 + 4];
            int slot_t = __float_as_int(gb[t * 8 + 5]);
            float xi1 = fmaxf(px1, bx1), yi1 = fmaxf(py1, by1);
            float xi2 = fminf(px2, bx2), yi2 = fminf(py2, by2);
            float iw = fmaxf(xi2 - xi1, 0.0f), ih = fmaxf(yi2 - yi1, 0.0f);
            float inter = iw * ih;
            float iou = inter * __builtin_amdgcn_rcpf(parea + area - inter);
            m = fmaxf(m, iou);
            if (slot_t == s) w = t;   // ascending t => last valid wins
        }
        anyf = (m > IGNORE_THRESH) ? 1 : 0;

        float conf = fast_sigmoid(o4);
        if (w >= 0) {
            // assigned: conf MSE at OBJ scale + box MSE + class CE
            float d = (conf - m) * OBJ_SCALE;
            loss += 0.5f * d * d;
            const float* tb = gtb + ((size_t)b * T + w) * 8;  // divergent w: v-load
            float d0 = s0 - tb[0], d1 = s1 - tb[1];
            float d2 = e2 - tb[2], d3 = e3 - tb[3];
            loss += 0.5f * (d0 * d0 + d1 * d1 + d2 * d2 + d3 * d3);

            float v[NC];
            #pragma unroll
            for (int c = 0; c < NC; ++c) v[c] = ob[(5 + c) * K + k];
            float mx = v[0];
            #pragma unroll
            for (int c = 1; c < NC; ++c) mx = fmaxf(mx, v[c]);
            float se = 0.0f;
            #pragma unroll
            for (int c = 0; c < NC; ++c) se += __expf(v[c] - mx);
            int cls = (int)tb[4];
            loss += (__logf(se) + mx) - v[cls];
        } else {
            // unassigned: noobj term (NOOBJ_SCALE=1); cancelled later if pos_any
            float term = 0.5f * conf * conf;
            loss += term;
            if (m >= IGNORE_THRESH) masked += term;
        }
    }

    // ---- block reduce partials ----
    for (int off = 32; off > 0; off >>= 1) {
        loss   += __shfl_down(loss, off);
        masked += __shfl_down(masked, off);
    }
    anyf = __any(anyf) ? 1 : 0;
    int lane = tid & 63, wv = tid >> 6;
    if (lane == 0) { redl[wv] = loss; redm[wv] = masked; reda[wv] = anyf; }
    __syncthreads();
    if (tid == 0) {
        int idx = b * GCH + blockIdx.x;
        Lp[idx]   = redl[0] + redl[1] + redl[2] + redl[3];
        Mp[idx]   = redm[0] + redm[1] + redm[2] + redm[3];
        Anyp[idx] = reda[0] | reda[1] | reda[2] | reda[3];
        __threadfence();                       // publish partials device-wide
        unsigned old = atomicAdd(cnt, 1u);     // device-scope
        lastFlag = (old == (unsigned)(NBLK - 1));
    }
    __syncthreads();

    // ---- last finishing block: global reduce + pos_any fix + final store ----
    if (lastFlag) {
        __threadfence();
        float acc = 0.0f;
        if (tid < BN) {
            float L = 0.0f, M = 0.0f;
            int any = 0;
            #pragma unroll
            for (int c = 0; c < GCH; ++c) {
                int idx = tid * GCH + c;
                L += Lp[idx];
                M += Mp[idx];
                any |= Anyp[idx];
            }
            acc = L - (any ? M : 0.0f);
        }
        for (int off = 32; off > 0; off >>= 1) acc += __shfl_down(acc, off);
        if (lane == 0) redl[wv] = acc;
        __syncthreads();
        if (tid == 0)
            out[0] = (redl[0] + redl[1] + redl[2] + redl[3]) * (1.0f / (float)BN);
    }
}

extern "C" void kernel_launch(void* const* d_in, const int* in_sizes, int n_in,
                              void* d_out, int out_size, void* d_ws, size_t ws_size,
                              hipStream_t stream) {
    const float* outputs = (const float*)d_in[0];
    const float* targets = (const float*)d_in[1];
    float* out = (float*)d_out;

    // ws layout (all written before read; counter zero-init'd by K0):
    float*    giou = (float*)d_ws;                       // BN*T*8 floats (200 KB)
    float*    gtb  = giou + (size_t)BN * T * 8;          // BN*T*8 floats
    float*    Lp   = gtb + (size_t)BN * T * 8;           // NBLK
    float*    Mp   = Lp + NBLK;                          // NBLK
    int*      Anyp = (int*)(Mp + NBLK);                  // NBLK
    unsigned* cnt  = (unsigned*)(Anyp + NBLK);           // 1

    yolo_prep<<<(BN * T + 255) / 256, 256, 0, stream>>>(targets, giou, gtb, cnt);
    yolo_main<<<dim3(GCH, BN), 256, 0, stream>>>(outputs, giou, gtb,
                                                 Lp, Mp, Anyp, cnt, out);
}

// Round 6
// 108.390 us; speedup vs baseline: 1.2519x; 1.2519x over previous
//
#include <hip/hip_runtime.h>
#include <math.h>

// Problem constants (match reference)
constexpr int BN = 128;
constexpr int FH = 26, FW = 26;
constexpr int T  = 50;
constexpr int A  = 5;
constexpr int NC = 20;
constexpr int K  = FH * FW;      // 676
constexpr int KA = K * A;        // 3380
constexpr int CH = A * (5 + NC); // 125

constexpr float IGNORE_THRESH = 0.75f;
constexpr float OBJ_SCALE = 5.0f;
// NOOBJ_SCALE = 1.0 (folded into the math)

constexpr int NPAIR = KA / 2;                 // 1690 slot-pairs per batch
constexpr int PPP   = K / 2;                  // 338 pairs per anchor plane
constexpr int GCH   = (NPAIR + 255) / 256;    // 7 chunks of 256 pairs
constexpr int NBLK  = BN * GCH;               // 896 main blocks

__constant__ float ANCW[A] = {1.3221f, 3.19275f, 5.05587f, 9.47112f, 11.2364f};
__constant__ float ANCH[A] = {1.73145f, 4.00944f, 8.09892f, 4.84053f, 10.0071f};

__device__ __forceinline__ float fast_sigmoid(float x) {
    return __builtin_amdgcn_rcpf(1.0f + __expf(-x));
}

// ---------------------------------------------------------------------------
// K0: per-GT decode, one thread per (b,t).
//   rec[b][t]  = 8 floats: {x1,y1,x2,y2, slot_bits, cls, 0,0}
//                (box degenerate if invalid -> inter==0; slot=-1 if invalid)
//   tbrec[b][t]= 4 floats: {tb0,tb1,tb2,tb3}
// Also zero-inits the completion counter for K1's last-block reduce.
// ---------------------------------------------------------------------------
__global__ __launch_bounds__(256) void yolo_prep(
        const float* __restrict__ targets,
        float* __restrict__ rec, float* __restrict__ tbrec,
        unsigned* __restrict__ cnt) {
    int i = blockIdx.x * 256 + threadIdx.x;
    if (i == 0) *cnt = 0u;
    if (i >= BN * T) return;

    const float* g = targets + (size_t)i * 5;
    float rx1 = g[0], ry1 = g[1], rx2 = g[2], ry2 = g[3];
    bool valid = (rx1 + ry1 + rx2 + ry2) > 0.0f;
    float x1 = rx1 * FW, y1 = ry1 * FH, x2 = rx2 * FW, y2 = ry2 * FH;
    float w = x2 - x1, h = y2 - y1;

    float cxf = 0.5f * (x1 + x2), cyf = 0.5f * (y1 + y2);
    int cx = (int)floorf(cxf); cx = min(max(cx, 0), FW - 1);
    int cy = (int)floorf(cyf); cy = min(max(cy, 0), FH - 1);
    int cell = cy * FW + cx;

    // argmax over anchors (strict > => first max wins) of IoU(anchor@center, gt)
    float acx = (float)cx + 0.5f, acy = (float)cy + 0.5f;
    float best = -1.0f; int ai = 0;
    for (int a = 0; a < A; ++a) {
        float aw = ANCW[a], ah = ANCH[a];
        float xi1 = fmaxf(acx - 0.5f * aw, x1), yi1 = fmaxf(acy - 0.5f * ah, y1);
        float xi2 = fminf(acx + 0.5f * aw, x2), yi2 = fminf(acy + 0.5f * ah, y2);
        float inter = fmaxf(xi2 - xi1, 0.0f) * fmaxf(yi2 - yi1, 0.0f);
        float iou = inter / (aw * ah + w * h - inter);
        if (iou > best) { best = iou; ai = a; }
    }

    float4 p0;
    int slot;
    if (valid) {
        p0 = make_float4(x1, y1, x2, y2);
        slot = ai * K + cell;
    } else {
        p0 = make_float4(1e18f, 1e18f, -1e18f, -1e18f);  // inter -> 0, area huge -> iou 0
        slot = -1;
    }
    *(float4*)(rec + (size_t)i * 8)     = p0;
    *(float4*)(rec + (size_t)i * 8 + 4) = make_float4(__int_as_float(slot), g[4], 0.0f, 0.0f);
    *(float4*)(tbrec + (size_t)i * 4)   = make_float4(cxf - (float)cx, cyf - (float)cy,
                                                      w / ANCW[ai], h / ANCH[ai]);
}

// ---------------------------------------------------------------------------
// K1: main pass. grid (GCH, BN) = 896 blocks, 256 threads, TWO adjacent slots
// per thread (k pair; K even so a pair never crosses an anchor plane).
//  - GT records staged into LDS with 100 coalesced float4 loads (no decode).
//  - Winner resolution OUT of the IoU loop: per-block 512-entry LDS table,
//    atomicMax over t (== lax.scan last-valid-wins). Thread's slots are
//    wtab[2*tid] / wtab[2*tid+1].
//  - IoU loop reads ONE b128 (box) per GT; area recomputed (exact ref math).
//  - pos_any deferred (noobj term unconditional, m>=thresh subset in Mp);
//    LAST finishing block (device atomic counter, zeroed by K0) reduces all
//    partials:  out = [ sum_b (L_b - any_b * M_b) ] / BN
// ---------------------------------------------------------------------------
__global__ __launch_bounds__(256) void yolo_main(
        const float* __restrict__ outputs,   // (B, 125, 26, 26)
        const float* __restrict__ rec, const float* __restrict__ tbrec,
        float* __restrict__ Lp, float* __restrict__ Mp, int* __restrict__ Anyp,
        unsigned* __restrict__ cnt, float* __restrict__ out) {
    __shared__ float4 srec[T * 2];   // [2t]=box, [2t+1]={slot,cls,0,0}
    __shared__ int    wtab[512];
    __shared__ float  redl[4], redm[4];
    __shared__ int    reda[4];
    __shared__ int    lastFlag;

    const int b   = blockIdx.y;
    const int tid = threadIdx.x;
    const int p   = blockIdx.x * 256 + tid;      // pair id
    const bool live = p < NPAIR;
    const int a   = live ? (p / PPP) : 0;
    const int k0  = (p - a * PPP) * 2;           // k of first slot in pair
    const float* ob = outputs + (size_t)b * CH * K + (size_t)(a * 25) * K;

    // issue pred loads early (independent of LDS staging)
    float2 o0, o1, o2, o3, o4;
    if (live) {
        o0 = *(const float2*)(ob + 0 * K + k0);
        o1 = *(const float2*)(ob + 1 * K + k0);
        o2 = *(const float2*)(ob + 2 * K + k0);
        o3 = *(const float2*)(ob + 3 * K + k0);
        o4 = *(const float2*)(ob + 4 * K + k0);
    }

    // stage GT records + init winner table
    if (tid < T * 2) srec[tid] = ((const float4*)(rec + (size_t)b * T * 8))[tid];
    wtab[tid] = -1;
    wtab[tid + 256] = -1;
    __syncthreads();

    if (tid < T) {
        int slot = __float_as_int(srec[tid * 2 + 1].x);
        int local = slot - blockIdx.x * 512;     // block covers slots [x*512, +512)
        if (slot >= 0 && (unsigned)local < 512u) atomicMax(&wtab[local], tid);
    }
    __syncthreads();

    float loss = 0.0f, masked = 0.0f;
    int anyf = 0;

    if (live) {
        float s0a = fast_sigmoid(o0.x), s0b = fast_sigmoid(o0.y);
        float s1a = fast_sigmoid(o1.x), s1b = fast_sigmoid(o1.y);
        float e2a = __expf(o2.x),       e2b = __expf(o2.y);
        float e3a = __expf(o3.x),       e3b = __expf(o3.y);

        const int yy = k0 / FW, xx = k0 - yy * FW;   // slot0 coords; slot1 x+1 (pair
        const int yy1 = (k0 + 1) / FW, xx1 = (k0 + 1) - yy1 * FW;

        float pxa = (float)xx  + s0a, pya = (float)yy  + s1a;
        float pxb = (float)xx1 + s0b, pyb = (float)yy1 + s1b;
        float pwa = ANCW[a] * e2a, pha = ANCH[a] * e3a;
        float pwb = ANCW[a] * e2b, phb = ANCH[a] * e3b;
        float ax1 = pxa - 0.5f * pwa, ax2 = pxa + 0.5f * pwa;
        float ay1 = pya - 0.5f * pha, ay2 = pya + 0.5f * pha;
        float bx1 = pxb - 0.5f * pwb, bx2 = pxb + 0.5f * pwb;
        float by1 = pyb - 0.5f * phb, by2 = pyb + 0.5f * phb;
        float pa = pwa * pha, pb = pwb * phb;

        float ma = -1.0f, mb = -1.0f;
        #pragma unroll 5
        for (int t = 0; t < T; ++t) {
            float4 bx = srec[t * 2];
            float gw = bx.z - bx.x, gh = bx.w - bx.y;
            float garea = gw * gh;
            // slot 0
            {
                float xi1 = fmaxf(ax1, bx.x), yi1 = fmaxf(ay1, bx.y);
                float xi2 = fminf(ax2, bx.z), yi2 = fminf(ay2, bx.w);
                float inter = fmaxf(xi2 - xi1, 0.0f) * fmaxf(yi2 - yi1, 0.0f);
                ma = fmaxf(ma, inter * __builtin_amdgcn_rcpf(pa + garea - inter));
            }
            // slot 1
            {
                float xi1 = fmaxf(bx1, bx.x), yi1 = fmaxf(by1, bx.y);
                float xi2 = fminf(bx2, bx.z), yi2 = fminf(by2, bx.w);
                float inter = fmaxf(xi2 - xi1, 0.0f) * fmaxf(yi2 - yi1, 0.0f);
                mb = fmaxf(mb, inter * __builtin_amdgcn_rcpf(pb + garea - inter));
            }
        }
        anyf = ((ma > IGNORE_THRESH) || (mb > IGNORE_THRESH)) ? 1 : 0;

        const float mm[2]   = {ma, mb};
        const float confv[2] = {fast_sigmoid(o4.x), fast_sigmoid(o4.y)};
        const float s0v[2] = {s0a, s0b}, s1v[2] = {s1a, s1b};
        const float e2v[2] = {e2a, e2b}, e3v[2] = {e3a, e3b};

        #pragma unroll
        for (int j = 0; j < 2; ++j) {
            int w = wtab[2 * tid + j];
            float m = mm[j], conf = confv[j];
            if (w >= 0) {
                // assigned: conf MSE at OBJ scale + box MSE + class CE
                float d = (conf - m) * OBJ_SCALE;
                loss += 0.5f * d * d;
                const float* tb = tbrec + ((size_t)b * T + w) * 4;  // rare lanes
                float d0 = s0v[j] - tb[0], d1 = s1v[j] - tb[1];
                float d2 = e2v[j] - tb[2], d3 = e3v[j] - tb[3];
                loss += 0.5f * (d0 * d0 + d1 * d1 + d2 * d2 + d3 * d3);

                float v[NC];
                #pragma unroll
                for (int c = 0; c < NC; ++c) v[c] = ob[(5 + c) * K + k0 + j];
                float mx = v[0];
                #pragma unroll
                for (int c = 1; c < NC; ++c) mx = fmaxf(mx, v[c]);
                float se = 0.0f;
                #pragma unroll
                for (int c = 0; c < NC; ++c) se += __expf(v[c] - mx);
                int cls = (int)srec[2 * w + 1].y;
                loss += (__logf(se) + mx) - v[cls];
            } else {
                // unassigned: noobj term (NOOBJ_SCALE=1); cancelled later if pos_any
                float term = 0.5f * conf * conf;
                loss += term;
                if (m >= IGNORE_THRESH) masked += term;
            }
        }
    }

    // ---- block reduce partials ----
    for (int off = 32; off > 0; off >>= 1) {
        loss   += __shfl_down(loss, off);
        masked += __shfl_down(masked, off);
    }
    anyf = __any(anyf) ? 1 : 0;
    int lane = tid & 63, wv = tid >> 6;
    if (lane == 0) { redl[wv] = loss; redm[wv] = masked; reda[wv] = anyf; }
    __syncthreads();
    if (tid == 0) {
        int idx = b * GCH + blockIdx.x;
        Lp[idx]   = redl[0] + redl[1] + redl[2] + redl[3];
        Mp[idx]   = redm[0] + redm[1] + redm[2] + redm[3];
        Anyp[idx] = reda[0] | reda[1] | reda[2] | reda[3];
        __threadfence();                       // publish partials device-wide
        unsigned old = atomicAdd(cnt, 1u);     // device-scope
        lastFlag = (old == (unsigned)(NBLK - 1));
    }
    __syncthreads();

    // ---- last finishing block: global reduce + pos_any fix + final store ----
    if (lastFlag) {
        __threadfence();
        float acc = 0.0f;
        if (tid < BN) {
            float L = 0.0f, M = 0.0f;
            int any = 0;
            #pragma unroll
            for (int c = 0; c < GCH; ++c) {
                int idx = tid * GCH + c;
                L += Lp[idx];
                M += Mp[idx];
                any |= Anyp[idx];
            }
            acc = L - (any ? M : 0.0f);
        }
        for (int off = 32; off > 0; off >>= 1) acc += __shfl_down(acc, off);
        if (lane == 0) redl[wv] = acc;
        __syncthreads();
        if (tid == 0)
            out[0] = (redl[0] + redl[1] + redl[2] + redl[3]) * (1.0f / (float)BN);
    }
}

extern "C" void kernel_launch(void* const* d_in, const int* in_sizes, int n_in,
                              void* d_out, int out_size, void* d_ws, size_t ws_size,
                              hipStream_t stream) {
    const float* outputs = (const float*)d_in[0];
    const float* targets = (const float*)d_in[1];
    float* out = (float*)d_out;

    // ws layout (all written before read; counter zero-init'd by K0):
    float*    recb  = (float*)d_ws;                      // BN*T*8 floats (200 KB)
    float*    tbrec = recb + (size_t)BN * T * 8;         // BN*T*4 floats (100 KB)
    float*    Lp    = tbrec + (size_t)BN * T * 4;        // NBLK
    float*    Mp    = Lp + NBLK;                         // NBLK
    int*      Anyp  = (int*)(Mp + NBLK);                 // NBLK
    unsigned* cnt   = (unsigned*)(Anyp + NBLK);          // 1

    yolo_prep<<<(BN * T + 255) / 256, 256, 0, stream>>>(targets, recb, tbrec, cnt);
    yolo_main<<<dim3(GCH, BN), 256, 0, stream>>>(outputs, recb, tbrec,
                                                 Lp, Mp, Anyp, cnt, out);
}

// Round 7
// 92.061 us; speedup vs baseline: 1.4739x; 1.1774x over previous
//
#include <hip/hip_runtime.h>
#include <math.h>

// Problem constants (match reference)
constexpr int BN = 128;
constexpr int FH = 26, FW = 26;
constexpr int T  = 50;
constexpr int A  = 5;
constexpr int NC = 20;
constexpr int K  = FH * FW;      // 676
constexpr int KA = K * A;        // 3380
constexpr int CH = A * (5 + NC); // 125

constexpr float IGNORE_THRESH = 0.75f;
constexpr float OBJ_SCALE = 5.0f;
// NOOBJ_SCALE = 1.0 (folded into the math)

constexpr int GCH   = (KA + 255) / 256;   // 14 chunks of 256 slots per batch
constexpr int NPART = BN * GCH;           // 1792 partials

__constant__ float ANCW[A] = {1.3221f, 3.19275f, 5.05587f, 9.47112f, 11.2364f};
__constant__ float ANCH[A] = {1.73145f, 4.00944f, 8.09892f, 4.84053f, 10.0071f};

__device__ __forceinline__ float fast_sigmoid(float x) {
    return __builtin_amdgcn_rcpf(1.0f + __expf(-x));
}

// ---------------------------------------------------------------------------
// Main pass: grid (GCH, BN) = 1792 blocks (28 waves/CU — R3's proven TLP),
// one thread per slot.
//  - 5 pred-plane loads issued BEFORE the decode barriers (latency overlap).
//  - threads 0..T-1 decode the 50 GTs into LDS (box/tb/cls); winner resolved
//    via per-block 256-entry wtab with LDS atomicMax over t (== lax.scan
//    last-valid-wins) — removes the per-iteration slot compare AND the second
//    DS read: the IoU loop is ONE ds_read_b128 + ~16 VALU per GT, area
//    recomputed with the identical ref expression.
//  - pos_any deferred: noobj term unconditional, m>=thresh subset in Mp;
//    fix kernel computes out = [ sum_b (L_b - any_b * M_b) ] / BN.
// No global atomics, no zero-init anywhere.
// ---------------------------------------------------------------------------
__global__ __launch_bounds__(256) void yolo_main(
        const float* __restrict__ outputs,   // (B, 125, 26, 26)
        const float* __restrict__ targets,   // (B, 50, 5)
        float* __restrict__ Lp, float* __restrict__ Mp, int* __restrict__ Anyp) {
    __shared__ float4 sbox[T];    // x1,y1,x2,y2 (degenerate if invalid)
    __shared__ float4 stb[T];     // tb0..tb3
    __shared__ float  scls[T];
    __shared__ int    wtab[256];  // winner t per local slot, -1 if none
    __shared__ float  redl[4], redm[4];
    __shared__ int    reda[4];

    const int b    = blockIdx.y;
    const int tid  = threadIdx.x;
    const int base = blockIdx.x * 256;
    const int s    = base + tid;
    const bool live = s < KA;

    // ---- issue pred loads first (independent of LDS), overlap decode ----
    const int a = live ? (s / K) : 0;
    const int k = live ? (s - a * K) : 0;
    const float* ob = outputs + (size_t)b * CH * K + (size_t)(a * 25) * K;
    float o0 = 0, o1 = 0, o2 = 0, o3 = 0, o4 = 0;
    if (live) {
        o0 = ob[0 * K + k];
        o1 = ob[1 * K + k];
        o2 = ob[2 * K + k];
        o3 = ob[3 * K + k];
        o4 = ob[4 * K + k];
    }

    // ---- phase 1: winner-table init + GT decode ----
    wtab[tid] = -1;
    int myslot = -1;
    if (tid < T) {
        const float* gt = targets + ((size_t)b * T + tid) * 5;
        float rx1 = gt[0], ry1 = gt[1], rx2 = gt[2], ry2 = gt[3];
        bool valid = (rx1 + ry1 + rx2 + ry2) > 0.0f;
        float x1 = rx1 * FW, y1 = ry1 * FH, x2 = rx2 * FW, y2 = ry2 * FH;
        float w = x2 - x1, h = y2 - y1;

        float cxf = 0.5f * (x1 + x2), cyf = 0.5f * (y1 + y2);
        int cx = (int)floorf(cxf); cx = min(max(cx, 0), FW - 1);
        int cy = (int)floorf(cyf); cy = min(max(cy, 0), FH - 1);
        int cell = cy * FW + cx;

        // argmax over anchors (strict > => first max wins)
        float acx = (float)cx + 0.5f, acy = (float)cy + 0.5f;
        float best = -1.0f; int ai = 0;
        for (int aa = 0; aa < A; ++aa) {
            float aw = ANCW[aa], ah = ANCH[aa];
            float xi1 = fmaxf(acx - 0.5f * aw, x1), yi1 = fmaxf(acy - 0.5f * ah, y1);
            float xi2 = fminf(acx + 0.5f * aw, x2), yi2 = fminf(acy + 0.5f * ah, y2);
            float inter = fmaxf(xi2 - xi1, 0.0f) * fmaxf(yi2 - yi1, 0.0f);
            float iou = inter / (aw * ah + w * h - inter);
            if (iou > best) { best = iou; ai = aa; }
        }

        sbox[tid] = valid ? make_float4(x1, y1, x2, y2)
                          : make_float4(1e18f, 1e18f, -1e18f, -1e18f);  // inter->0
        stb[tid]  = make_float4(cxf - (float)cx, cyf - (float)cy,
                                w / ANCW[ai], h / ANCH[ai]);
        scls[tid] = gt[4];
        if (valid) myslot = ai * K + cell;
    }
    __syncthreads();

    // ---- phase 2: winner assignment (last valid t wins == atomicMax) ----
    if (myslot >= 0) {
        int local = myslot - base;
        if ((unsigned)local < 256u) atomicMax(&wtab[local], tid);
    }
    __syncthreads();

    float loss = 0.0f, masked = 0.0f;
    int anyf = 0;

    if (live) {
        const int yy = k / FW, xx = k - yy * FW;
        float s0 = fast_sigmoid(o0), s1 = fast_sigmoid(o1);
        float e2 = __expf(o2),       e3 = __expf(o3);
        float px = (float)xx + s0, py = (float)yy + s1;
        float pw = ANCW[a] * e2,  ph = ANCH[a] * e3;
        float px1 = px - 0.5f * pw, px2 = px + 0.5f * pw;
        float py1 = py - 0.5f * ph, py2 = py + 0.5f * ph;
        float parea = pw * ph;

        float m = -1.0f;
        #pragma unroll 10
        for (int t = 0; t < T; ++t) {
            float4 bx = sbox[t];
            float garea = (bx.z - bx.x) * (bx.w - bx.y);   // ref's a2 expression
            float xi1 = fmaxf(px1, bx.x), yi1 = fmaxf(py1, bx.y);
            float xi2 = fminf(px2, bx.z), yi2 = fminf(py2, bx.w);
            float iw = fmaxf(xi2 - xi1, 0.0f), ih = fmaxf(yi2 - yi1, 0.0f);
            float inter = iw * ih;
            float iou = inter * __builtin_amdgcn_rcpf(parea + garea - inter);
            m = fmaxf(m, iou);
        }
        anyf = (m > IGNORE_THRESH) ? 1 : 0;

        float conf = fast_sigmoid(o4);
        int w = wtab[tid];
        if (w >= 0) {
            // assigned: conf MSE at OBJ scale + box MSE + class CE
            float d = (conf - m) * OBJ_SCALE;
            loss += 0.5f * d * d;
            float4 tb = stb[w];
            float d0 = s0 - tb.x, d1 = s1 - tb.y;
            float d2 = e2 - tb.z, d3 = e3 - tb.w;
            loss += 0.5f * (d0 * d0 + d1 * d1 + d2 * d2 + d3 * d3);

            float v[NC];
            #pragma unroll
            for (int c = 0; c < NC; ++c) v[c] = ob[(5 + c) * K + k];
            float mx = v[0];
            #pragma unroll
            for (int c = 1; c < NC; ++c) mx = fmaxf(mx, v[c]);
            float se = 0.0f;
            #pragma unroll
            for (int c = 0; c < NC; ++c) se += __expf(v[c] - mx);
            int cls = (int)scls[w];
            loss += (__logf(se) + mx) - v[cls];
        } else {
            // unassigned: noobj term (NOOBJ_SCALE=1); cancelled later if pos_any
            float term = 0.5f * conf * conf;
            loss += term;
            if (m >= IGNORE_THRESH) masked += term;
        }
    }

    // ---- block reduce ----
    for (int off = 32; off > 0; off >>= 1) {
        loss   += __shfl_down(loss, off);
        masked += __shfl_down(masked, off);
    }
    anyf = __any(anyf) ? 1 : 0;
    int lane = tid & 63, wv = tid >> 6;
    if (lane == 0) { redl[wv] = loss; redm[wv] = masked; reda[wv] = anyf; }
    __syncthreads();
    if (tid == 0) {
        int idx = b * GCH + blockIdx.x;
        Lp[idx]   = redl[0] + redl[1] + redl[2] + redl[3];
        Mp[idx]   = redm[0] + redm[1] + redm[2] + redm[3];
        Anyp[idx] = reda[0] | reda[1] | reda[2] | reda[3];
    }
}

// ---------------------------------------------------------------------------
// Fix/reduce: thread b folds its 14 chunk-partials, applies the pos_any
// correction, block-reduces 128 values, single plain store of the scalar.
// ---------------------------------------------------------------------------
__global__ __launch_bounds__(128) void yolo_fix(
        const float* __restrict__ Lp, const float* __restrict__ Mp,
        const int* __restrict__ Anyp, float* __restrict__ out) {
    __shared__ float red[2];
    int tid = threadIdx.x;
    float L = 0.0f, M = 0.0f;
    int any = 0;
    if (tid < BN) {
        #pragma unroll
        for (int c = 0; c < GCH; ++c) {
            int idx = tid * GCH + c;
            L += Lp[idx];
            M += Mp[idx];
            any |= Anyp[idx];
        }
    }
    float acc = L - (any ? M : 0.0f);
    for (int off = 32; off > 0; off >>= 1) acc += __shfl_down(acc, off);
    if ((tid & 63) == 0) red[tid >> 6] = acc;
    __syncthreads();
    if (tid == 0) out[0] = (red[0] + red[1]) * (1.0f / (float)BN);
}

extern "C" void kernel_launch(void* const* d_in, const int* in_sizes, int n_in,
                              void* d_out, int out_size, void* d_ws, size_t ws_size,
                              hipStream_t stream) {
    const float* outputs = (const float*)d_in[0];
    const float* targets = (const float*)d_in[1];
    float* out = (float*)d_out;

    // ws layout: Lp[1792] | Mp[1792] | Anyp[1792]  (~21 KB, written before read)
    float* Lp   = (float*)d_ws;
    float* Mp   = Lp + NPART;
    int*   Anyp = (int*)(Mp + NPART);

    yolo_main<<<dim3(GCH, BN), 256, 0, stream>>>(outputs, targets, Lp, Mp, Anyp);
    yolo_fix<<<1, 128, 0, stream>>>(Lp, Mp, Anyp, out);
}